// Round 12
// baseline (261.226 us; speedup 1.0000x reference)
//
#include <hip/hip_runtime.h>

// z_i = mu[a_i] + tril(cov[a_i]) @ eps_i   (B=4194304, A=64, D=8)
//
// History:
//  R4 (44x b32 LDS gather):  89.2us, conflicts 5.8M, BW 2.4TB/s, VALU 7.5%
//  R7 (consecutive-row ILP): 387us — broke coalescing. reverted.
//  R8 (grid-stride ILP x4):  97.5us — ILP null => not VMEM-latency-bound.
//  R9 (14x b128 LDS gather): 86.8us — conflicts UP to 9.9M, timing flat =>
//      LDS instr count alone isn't it either.
// v5 ablation: conflict-free gather via wave crossbar. A=64 == wavefront:
//  lane l holds annotator l's tril(L)+mu in 44 VGPRs (loaded once per wave
//  from LDS, conflict-free: stride-65 => bank=(l+off)%32, 2 lanes/bank).
//  Per row: 44 ds_bpermute (__shfl per-lane index a_i) — zero bank
//  conflicts by construction, no per-row LDS addressing.
//  Everything else identical to R4: 1 row/thread, 2048x256, float4 I/O.
// Decision: conflicts ->0 AND dur -> 60-70us  => gather pipe was the
//  co-bottleneck; iterate there. dur flat => memory-path ceiling ~2.4TB/s.

#define THREADS 256
#define A_CNT 64
#define L_STRIDE 65   // 64 + 1 pad: bank(l*65+k) = (l+k)%32 -> 2 lanes/bank
#define MU_STRIDE 9

__global__ __launch_bounds__(THREADS) void latent_rsample_v5(
    const int* __restrict__ annot,
    const float* __restrict__ eps,
    const float* __restrict__ mu,
    const float* __restrict__ cov,
    float* __restrict__ out,
    int B)
{
    __shared__ float L_lds[A_CNT * L_STRIDE];
    __shared__ float mu_lds[A_CNT * MU_STRIDE];

    // Stage tables (coalesced, once per block) — same as R4.
    for (int e = threadIdx.x; e < A_CNT * 64; e += THREADS) {
        int a  = e >> 6;
        int rc = e & 63;
        L_lds[a * L_STRIDE + rc] = cov[e];
    }
    for (int e = threadIdx.x; e < A_CNT * 8; e += THREADS) {
        int a = e >> 3;
        int r = e & 7;
        mu_lds[a * MU_STRIDE + r] = mu[e];
    }
    __syncthreads();

    // One-time: lane l caches annotator l's table in registers.
    // 44 conflict-free b32 reads per lane (2 lanes/bank — free on CDNA4).
    const int lane = threadIdx.x & 63;
    float Lt[36];
    {
        int k = 0;
        #pragma unroll
        for (int r = 0; r < 8; ++r)
            #pragma unroll
            for (int c = 0; c <= r; ++c)
                Lt[k++] = L_lds[lane * L_STRIDE + r * 8 + c];
    }
    float Mt[8];
    #pragma unroll
    for (int r = 0; r < 8; ++r)
        Mt[r] = mu_lds[lane * MU_STRIDE + r];

    const int stride = gridDim.x * THREADS;
    for (int i = blockIdx.x * THREADS + threadIdx.x; i < B; i += stride) {
        const int a = annot[i];                 // bpermute source lane

        const float4* ep = reinterpret_cast<const float4*>(eps + (size_t)i * 8);
        const float4 E0 = ep[0];
        const float4 E1 = ep[1];
        const float ef[8] = {E0.x, E0.y, E0.z, E0.w, E1.x, E1.y, E1.z, E1.w};

        // Gather annotator a's row data via wave crossbar (no bank conflicts).
        float z[8];
        {
            int k = 0;
            #pragma unroll
            for (int r = 0; r < 8; ++r) {
                float acc = __shfl(Mt[r], a, 64);
                #pragma unroll
                for (int c = 0; c <= r; ++c)    // tril
                    acc += __shfl(Lt[k++], a, 64) * ef[c];
                z[r] = acc;
            }
        }

        float4* op = reinterpret_cast<float4*>(out + (size_t)i * 8);
        op[0] = make_float4(z[0], z[1], z[2], z[3]);
        op[1] = make_float4(z[4], z[5], z[6], z[7]);
    }
}

extern "C" void kernel_launch(void* const* d_in, const int* in_sizes, int n_in,
                              void* d_out, int out_size, void* d_ws, size_t ws_size,
                              hipStream_t stream) {
    const int*   annot = (const int*)  d_in[0];   // [B] int32
    const float* eps   = (const float*)d_in[1];   // [B, 8] f32
    const float* mu    = (const float*)d_in[2];   // [64, 8] f32
    const float* cov   = (const float*)d_in[3];   // [64, 8, 8] f32
    float* out = (float*)d_out;                   // [B, 8] f32

    const int B = in_sizes[0];                    // 4194304
    const int blocks = 2048;                      // 8 grid-stride rows/thread

    latent_rsample_v5<<<blocks, THREADS, 0, stream>>>(annot, eps, mu, cov, out, B);
}